// Round 1
// baseline (555.102 us; speedup 1.0000x reference)
//
#include <hip/hip_runtime.h>
#include <hip/hip_bf16.h>
#include <stdint.h>

// Problem: out[b,s,o] = alpha * sum_k x[b,s,k] * t[o,k],  t in {-1,0,+1}
// M = 4*2048 = 8192, K = 4096, N = 4096.
#define M_DIM 8192
#define K_DIM 4096
#define N_DIM 4096

typedef __attribute__((ext_vector_type(8))) short short8;
typedef __attribute__((ext_vector_type(4))) float f32x4;

// ---------------------------------------------------------------------------
// async global->LDS, 16B per lane (global_load_lds_dwordx4)
// ---------------------------------------------------------------------------
__device__ __forceinline__ void lds_load16(const ushort* g, ushort* l) {
    __builtin_amdgcn_global_load_lds(
        (const __attribute__((address_space(1))) uint32_t*)g,
        (__attribute__((address_space(3))) uint32_t*)l, 16, 0, 0);
}

__device__ __forceinline__ ushort f2bf_rne(float f) {
    uint32_t u = __float_as_uint(f);
    uint32_t r = (u + 0x7FFFu + ((u >> 16) & 1u)) >> 16;
    return (ushort)r;
}

// ---------------------------------------------------------------------------
// Pass 1a: per-block partial sums of |w|, fp64 accumulate (deterministic)
// ---------------------------------------------------------------------------
__global__ void k_abs_partial(const float* __restrict__ w, double* __restrict__ partial) {
    const float4* w4 = (const float4*)w;
    const int n4 = (K_DIM * N_DIM) / 4;  // 4194304
    double s = 0.0;
    for (int i = blockIdx.x * blockDim.x + threadIdx.x; i < n4; i += gridDim.x * blockDim.x) {
        float4 v = w4[i];
        s += (double)fabsf(v.x) + (double)fabsf(v.y) + (double)fabsf(v.z) + (double)fabsf(v.w);
    }
    #pragma unroll
    for (int off = 32; off > 0; off >>= 1) s += __shfl_down(s, off, 64);
    __shared__ double sm[4];
    int lane = threadIdx.x & 63, wv = threadIdx.x >> 6;
    if (lane == 0) sm[wv] = s;
    __syncthreads();
    if (threadIdx.x == 0) partial[blockIdx.x] = sm[0] + sm[1] + sm[2] + sm[3];
}

// Pass 1b: finalize alpha = mean(|w|)
__global__ void k_alpha(const double* __restrict__ partial, float* __restrict__ alpha_out) {
    double s = 0.0;
    for (int i = threadIdx.x; i < 1024; i += 256) s += partial[i];
    #pragma unroll
    for (int off = 32; off > 0; off >>= 1) s += __shfl_down(s, off, 64);
    __shared__ double sm[4];
    int lane = threadIdx.x & 63, wv = threadIdx.x >> 6;
    if (lane == 0) sm[wv] = s;
    __syncthreads();
    if (threadIdx.x == 0) {
        double total = sm[0] + sm[1] + sm[2] + sm[3];
        alpha_out[0] = (float)(total * (1.0 / 16777216.0));
    }
}

// ---------------------------------------------------------------------------
// Pass 2: quantize w -> ternary {-1,0,+1} as bf16 (N x K row-major)
// ---------------------------------------------------------------------------
__global__ void k_quant(const float* __restrict__ w, const float* __restrict__ alpha_p,
                        ushort* __restrict__ qw) {
    const float thr = 0.5f * alpha_p[0];
    int i = blockIdx.x * blockDim.x + threadIdx.x;  // one float4 per thread
    float4 v = ((const float4*)w)[i];
    ushort4 q;
    q.x = v.x > thr ? 0x3F80 : (v.x < -thr ? 0xBF80 : 0);
    q.y = v.y > thr ? 0x3F80 : (v.y < -thr ? 0xBF80 : 0);
    q.z = v.z > thr ? 0x3F80 : (v.z < -thr ? 0xBF80 : 0);
    q.w = v.w > thr ? 0x3F80 : (v.w < -thr ? 0xBF80 : 0);
    ((ushort4*)qw)[i] = q;
}

// Pass 3: cast x fp32 -> bf16 (RNE)
__global__ void k_cast(const float* __restrict__ x, ushort* __restrict__ xb) {
    int i = blockIdx.x * blockDim.x + threadIdx.x;  // one float4 per thread
    float4 v = ((const float4*)x)[i];
    ushort4 o;
    o.x = f2bf_rne(v.x);
    o.y = f2bf_rne(v.y);
    o.z = f2bf_rne(v.z);
    o.w = f2bf_rne(v.w);
    ((ushort4*)xb)[i] = o;
}

// ---------------------------------------------------------------------------
// Pass 4: bf16 MFMA GEMM, m97 structure: 128x128 tile, BK=64, 16x16x32 MFMA,
// global_load_lds width=16, B^T layout (B stored N x K). C = alpha * A @ B^T.
// ---------------------------------------------------------------------------
#define BM 128
#define BN 128
#define BK 64

__global__ __launch_bounds__(256, 2) void k_gemm(const ushort* __restrict__ A,  // M x K bf16
                                                 const ushort* __restrict__ B,  // N x K bf16
                                                 const float* __restrict__ alpha_p,
                                                 float* __restrict__ C) {
    __shared__ __align__(16) ushort sA[BM * BK];  // 16 KB
    __shared__ __align__(16) ushort sB[BN * BK];  // 16 KB

    const int tid = threadIdx.x;
    const int lane = tid & 63;
    const int bm = blockIdx.y, bn = blockIdx.x;
    const int wv = tid >> 6;
    const int wm = (wv & 1) * 64;   // wave's M offset in tile
    const int wn = (wv >> 1) * 64;  // wave's N offset in tile

    f32x4 acc[4][4] = {};

    const ushort* Abase = A + (size_t)(bm * BM) * K_DIM;
    const ushort* Bbase = B + (size_t)(bn * BN) * K_DIM;

    const int r = lane & 15, q = lane >> 4;

    for (int kb = 0; kb < K_DIM / BK; ++kb) {
        const int k0 = kb * BK;
        // stage A,B tiles: chunk c covers row c>>3, k-cols (c&7)*8..+8
        #pragma unroll
        for (int j = 0; j < 4; ++j) {
            int c = j * 256 + tid;
            int row = c >> 3, kc = (c & 7) * 8;
            lds_load16(Abase + (size_t)row * K_DIM + k0 + kc, &sA[c * 8]);
            lds_load16(Bbase + (size_t)row * K_DIM + k0 + kc, &sB[c * 8]);
        }
        __syncthreads();

        #pragma unroll
        for (int kk = 0; kk < BK; kk += 32) {
            short8 af[4], bfr[4];
            #pragma unroll
            for (int i = 0; i < 4; ++i)
                af[i] = *(const short8*)&sA[(wm + i * 16 + r) * BK + kk + q * 8];
            #pragma unroll
            for (int j = 0; j < 4; ++j)
                bfr[j] = *(const short8*)&sB[(wn + j * 16 + r) * BK + kk + q * 8];
            #pragma unroll
            for (int i = 0; i < 4; ++i)
                #pragma unroll
                for (int j = 0; j < 4; ++j)
                    acc[i][j] = __builtin_amdgcn_mfma_f32_16x16x32_bf16(af[i], bfr[j], acc[i][j], 0, 0, 0);
        }
        __syncthreads();
    }

    const float alpha = alpha_p[0];
    // C/D layout: col = lane&15, row = (lane>>4)*4 + reg   [m89-verified]
    #pragma unroll
    for (int i = 0; i < 4; ++i)
        #pragma unroll
        for (int j = 0; j < 4; ++j)
            #pragma unroll
            for (int v = 0; v < 4; ++v) {
                int row = bm * BM + wm + i * 16 + q * 4 + v;
                int col = bn * BN + wn + j * 16 + r;
                C[(size_t)row * N_DIM + col] = alpha * acc[i][j][v];
            }
}

// ---------------------------------------------------------------------------
extern "C" void kernel_launch(void* const* d_in, const int* in_sizes, int n_in,
                              void* d_out, int out_size, void* d_ws, size_t ws_size,
                              hipStream_t stream) {
    const float* x = (const float*)d_in[0];  // 4*2048*4096 fp32
    const float* w = (const float*)d_in[1];  // 4096*4096 fp32
    float* out = (float*)d_out;              // 8192*4096 fp32

    char* ws = (char*)d_ws;
    double* partial = (double*)ws;                          // 8 KB
    float* alpha = (float*)(ws + 8192);                     // 4 B
    ushort* qw = (ushort*)(ws + 16384);                     // 32 MB (N x K bf16 ternary)
    ushort* xb = (ushort*)(ws + 16384 + (size_t)K_DIM * N_DIM * 2);  // 64 MB (M x K bf16)

    k_abs_partial<<<1024, 256, 0, stream>>>(w, partial);
    k_alpha<<<1, 256, 0, stream>>>(partial, alpha);
    k_quant<<<(K_DIM * N_DIM / 4) / 256, 256, 0, stream>>>(w, alpha, qw);
    k_cast<<<(M_DIM * K_DIM / 4) / 256, 256, 0, stream>>>(x, xb);

    dim3 grid(N_DIM / BN, M_DIM / BM);  // 32 x 64 = 2048 blocks
    k_gemm<<<grid, dim3(256), 0, stream>>>(xb, qw, alpha, out);
}

// Round 2
// 546.669 us; speedup vs baseline: 1.0154x; 1.0154x over previous
//
#include <hip/hip_runtime.h>
#include <hip/hip_bf16.h>
#include <stdint.h>

// Problem: out[b,s,o] = alpha * sum_k x[b,s,k] * t[o,k],  t in {-1,0,+1}
// M = 4*2048 = 8192, K = 4096, N = 4096.
#define M_DIM 8192
#define K_DIM 4096
#define N_DIM 4096

typedef __attribute__((ext_vector_type(8))) short short8;
typedef __attribute__((ext_vector_type(4))) float f32x4;

// ---------------------------------------------------------------------------
// async global->LDS, 16B per lane (global_load_lds_dwordx4)
// ---------------------------------------------------------------------------
__device__ __forceinline__ void lds_load16(const ushort* g, ushort* l) {
    __builtin_amdgcn_global_load_lds(
        (const __attribute__((address_space(1))) uint32_t*)g,
        (__attribute__((address_space(3))) uint32_t*)l, 16, 0, 0);
}

__device__ __forceinline__ ushort f2bf_rne(float f) {
    uint32_t u = __float_as_uint(f);
    uint32_t r = (u + 0x7FFFu + ((u >> 16) & 1u)) >> 16;
    return (ushort)r;
}

// ---------------------------------------------------------------------------
// Pass 1a: per-block partial sums of |w|, fp64 accumulate (deterministic)
// ---------------------------------------------------------------------------
__global__ void k_abs_partial(const float* __restrict__ w, double* __restrict__ partial) {
    const float4* w4 = (const float4*)w;
    const int n4 = (K_DIM * N_DIM) / 4;  // 4194304
    double s = 0.0;
    for (int i = blockIdx.x * blockDim.x + threadIdx.x; i < n4; i += gridDim.x * blockDim.x) {
        float4 v = w4[i];
        s += (double)fabsf(v.x) + (double)fabsf(v.y) + (double)fabsf(v.z) + (double)fabsf(v.w);
    }
    #pragma unroll
    for (int off = 32; off > 0; off >>= 1) s += __shfl_down(s, off, 64);
    __shared__ double sm[4];
    int lane = threadIdx.x & 63, wv = threadIdx.x >> 6;
    if (lane == 0) sm[wv] = s;
    __syncthreads();
    if (threadIdx.x == 0) partial[blockIdx.x] = sm[0] + sm[1] + sm[2] + sm[3];
}

// Pass 1b: finalize alpha = mean(|w|)
__global__ void k_alpha(const double* __restrict__ partial, float* __restrict__ alpha_out) {
    double s = 0.0;
    for (int i = threadIdx.x; i < 1024; i += 256) s += partial[i];
    #pragma unroll
    for (int off = 32; off > 0; off >>= 1) s += __shfl_down(s, off, 64);
    __shared__ double sm[4];
    int lane = threadIdx.x & 63, wv = threadIdx.x >> 6;
    if (lane == 0) sm[wv] = s;
    __syncthreads();
    if (threadIdx.x == 0) {
        double total = sm[0] + sm[1] + sm[2] + sm[3];
        alpha_out[0] = (float)(total * (1.0 / 16777216.0));
    }
}

// ---------------------------------------------------------------------------
// Pass 2: quantize w -> ternary {-1,0,+1} as bf16 (N x K row-major)
// ---------------------------------------------------------------------------
__global__ void k_quant(const float* __restrict__ w, const float* __restrict__ alpha_p,
                        ushort* __restrict__ qw) {
    const float thr = 0.5f * alpha_p[0];
    int i = blockIdx.x * blockDim.x + threadIdx.x;  // one float4 per thread
    float4 v = ((const float4*)w)[i];
    ushort4 q;
    q.x = v.x > thr ? 0x3F80 : (v.x < -thr ? 0xBF80 : 0);
    q.y = v.y > thr ? 0x3F80 : (v.y < -thr ? 0xBF80 : 0);
    q.z = v.z > thr ? 0x3F80 : (v.z < -thr ? 0xBF80 : 0);
    q.w = v.w > thr ? 0x3F80 : (v.w < -thr ? 0xBF80 : 0);
    ((ushort4*)qw)[i] = q;
}

// Pass 3: cast x fp32 -> bf16 (RNE)
__global__ void k_cast(const float* __restrict__ x, ushort* __restrict__ xb) {
    int i = blockIdx.x * blockDim.x + threadIdx.x;  // one float4 per thread
    float4 v = ((const float4*)x)[i];
    ushort4 o;
    o.x = f2bf_rne(v.x);
    o.y = f2bf_rne(v.y);
    o.z = f2bf_rne(v.z);
    o.w = f2bf_rne(v.w);
    ((ushort4*)xb)[i] = o;
}

// ---------------------------------------------------------------------------
// Pass 4: bf16 MFMA GEMM, m97 structure: 128x128 tile, BK=64, 16x16x32 MFMA,
// global_load_lds width=16, B^T layout (B stored N x K). C = alpha * A @ B^T.
// ---------------------------------------------------------------------------
#define BM 128
#define BN 128
#define BK 64

__global__ __launch_bounds__(256, 2) void k_gemm(const ushort* __restrict__ A,  // M x K bf16
                                                 const ushort* __restrict__ B,  // N x K bf16
                                                 const float* __restrict__ alpha_p,
                                                 float* __restrict__ C) {
    __shared__ __align__(16) ushort sA[BM * BK];  // 16 KB
    __shared__ __align__(16) ushort sB[BN * BK];  // 16 KB

    const int tid = threadIdx.x;
    const int lane = tid & 63;
    const int bm = blockIdx.y, bn = blockIdx.x;
    const int wv = tid >> 6;
    const int wm = (wv & 1) * 64;   // wave's M offset in tile
    const int wn = (wv >> 1) * 64;  // wave's N offset in tile

    f32x4 acc[4][4] = {};

    const ushort* Abase = A + (size_t)(bm * BM) * K_DIM;
    const ushort* Bbase = B + (size_t)(bn * BN) * K_DIM;

    const int r = lane & 15, q = lane >> 4;

    for (int kb = 0; kb < K_DIM / BK; ++kb) {
        const int k0 = kb * BK;
        // stage A,B tiles: chunk c covers row c>>3, k-cols (c&7)*8..+8
        #pragma unroll
        for (int j = 0; j < 4; ++j) {
            int c = j * 256 + tid;
            int row = c >> 3, kc = (c & 7) * 8;
            lds_load16(Abase + (size_t)row * K_DIM + k0 + kc, &sA[c * 8]);
            lds_load16(Bbase + (size_t)row * K_DIM + k0 + kc, &sB[c * 8]);
        }
        __syncthreads();

        #pragma unroll
        for (int kk = 0; kk < BK; kk += 32) {
            short8 af[4], bfr[4];
            #pragma unroll
            for (int i = 0; i < 4; ++i)
                af[i] = *(const short8*)&sA[(wm + i * 16 + r) * BK + kk + q * 8];
            #pragma unroll
            for (int j = 0; j < 4; ++j)
                bfr[j] = *(const short8*)&sB[(wn + j * 16 + r) * BK + kk + q * 8];
            #pragma unroll
            for (int i = 0; i < 4; ++i)
                #pragma unroll
                for (int j = 0; j < 4; ++j)
                    acc[i][j] = __builtin_amdgcn_mfma_f32_16x16x32_bf16(af[i], bfr[j], acc[i][j], 0, 0, 0);
        }
        __syncthreads();
    }

    const float alpha = alpha_p[0];
    // C/D layout: col = lane&15, row = (lane>>4)*4 + reg   [m89-verified]
    #pragma unroll
    for (int i = 0; i < 4; ++i)
        #pragma unroll
        for (int j = 0; j < 4; ++j)
            #pragma unroll
            for (int v = 0; v < 4; ++v) {
                int row = bm * BM + wm + i * 16 + q * 4 + v;
                int col = bn * BN + wn + j * 16 + r;
                C[(size_t)row * N_DIM + col] = alpha * acc[i][j][v];
            }
}

// ---------------------------------------------------------------------------
extern "C" void kernel_launch(void* const* d_in, const int* in_sizes, int n_in,
                              void* d_out, int out_size, void* d_ws, size_t ws_size,
                              hipStream_t stream) {
    const float* x = (const float*)d_in[0];  // 4*2048*4096 fp32
    const float* w = (const float*)d_in[1];  // 4096*4096 fp32
    float* out = (float*)d_out;              // 8192*4096 fp32

    char* ws = (char*)d_ws;
    double* partial = (double*)ws;                          // 8 KB
    float* alpha = (float*)(ws + 8192);                     // 4 B
    ushort* qw = (ushort*)(ws + 16384);                     // 32 MB (N x K bf16 ternary)
    ushort* xb = (ushort*)(ws + 16384 + (size_t)K_DIM * N_DIM * 2);  // 64 MB (M x K bf16)

    k_abs_partial<<<1024, 256, 0, stream>>>(w, partial);
    k_alpha<<<1, 256, 0, stream>>>(partial, alpha);
    k_quant<<<(K_DIM * N_DIM / 4) / 256, 256, 0, stream>>>(w, alpha, qw);
    k_cast<<<(M_DIM * K_DIM / 4) / 256, 256, 0, stream>>>(x, xb);

    dim3 grid(N_DIM / BN, M_DIM / BM);  // 32 x 64 = 2048 blocks
    k_gemm<<<grid, dim3(256), 0, stream>>>(xb, qw, alpha, out);
}